// Round 6
// baseline (211.326 us; speedup 1.0000x reference)
//
#include <hip/hip_runtime.h>
#include <stdint.h>

// SelfCrossAttn bf16-MFMA pipeline v6. b=4, c=512, N=4096, HEADS=4.
// All GEMMs NT: C[m][n] = sum_k A[m][k]*B[n][k], operands k-contiguous.
// kk' = s*128+t permutation (s=n>>10, t=c&127) applied uniformly to P cols
// and vT' rows; sum over kk is order-agnostic.
//  prep      : W* fp32->bf16 (Wb) ; x[b][c][n] -> xT[b][n][c] bf16
//  gemm_qkv  : q/k[b][o][n] bf16 natural; V direct-stored as vT'[slab][e][kk']
//  qk_softmax: FUSED. Block owns 32 q-rows x all 512 kk' (full softmax rows
//              in MFMA accs). 8 waves, K-loop over e=1024; cross-wave
//              max/sum via LDS stats; P bf16 packed via LDS -> coalesced.
//              S is never materialized.
//  gemm_pv   : O = P.V' (A=P[qq][kk'], B=vT'[e][kk']); scatters into yT[n][c]
//  gemm_proj : out = Wproj @ y + bias + x (NT vs yT), fp32

typedef __attribute__((ext_vector_type(8))) short short8;
typedef __attribute__((ext_vector_type(4))) float f32x4;

typedef const __attribute__((address_space(1))) unsigned int* gas_ptr;
typedef __attribute__((address_space(3))) unsigned int* las_ptr;

#define ATTN_SCALE 0.08838834764831845f   // 128^-0.5

__device__ __forceinline__ unsigned short f2bf(float f) {
    union { float f; unsigned int u; } c; c.f = f;
    unsigned int u = c.u;
    u += 0x7fffu + ((u >> 16) & 1u);      // RNE
    return (unsigned short)(u >> 16);
}

__device__ __forceinline__ void gl_lds16(const void* g, void* l) {
    __builtin_amdgcn_global_load_lds((gas_ptr)(uintptr_t)g, (las_ptr)(uintptr_t)l,
                                     16, 0, 0);
}

// ---- shared MFMA core: 128x128 C-tile, 4 waves, BK=32, 16x16x32 bf16 ----
// PERMB: B rows are logical kk' -> physical slab row 4*(kk'&127) + (kk'>>7).
template<int LDA, int LDB, int KDIM, bool PERMB = false>
__device__ __forceinline__ void mfma_core(
    const unsigned short* __restrict__ A,
    const unsigned short* __restrict__ B,
    int m0, int n0,
    unsigned short* __restrict__ sA, unsigned short* __restrict__ sB,
    f32x4 acc[4][4])
{
    const int tid  = threadIdx.x;
    const int lane = tid & 63, wave = tid >> 6;
    const int lr = lane >> 2, lc = lane & 3;       // staging: 16 rows x 4 chunks
    const int wm = (wave & 1) * 64, wn = (wave >> 1) * 64;
    const int col = lane & 15, quad = lane >> 4;

    const unsigned short* ga = A + (size_t)(m0 + 32 * wave + lr) * LDA + lc * 8;
    int rb0 = n0 + 32 * wave + lr;
    int rb1 = rb0 + 16;
    if (PERMB) {
        rb0 = 4 * (rb0 & 127) + (rb0 >> 7);
        rb1 = 4 * (rb1 & 127) + (rb1 >> 7);
    }
    const unsigned short* gb0 = B + (size_t)rb0 * LDB + lc * 8;
    const unsigned short* gb1 = B + (size_t)rb1 * LDB + lc * 8;

    unsigned short* la0 = sA + (32 * wave) * 32;
    unsigned short* la1 = sA + (32 * wave + 16) * 32;
    unsigned short* lb0 = sB + (32 * wave) * 32;
    unsigned short* lb1 = sB + (32 * wave + 16) * 32;

    for (int k0 = 0; k0 < KDIM; k0 += 32) {
        gl_lds16(ga + k0,            la0);
        gl_lds16(ga + k0 + 16 * LDA, la1);
        gl_lds16(gb0 + k0,           lb0);
        gl_lds16(gb1 + k0,           lb1);
        __syncthreads();
        short8 af[4], bf[4];
        #pragma unroll
        for (int i = 0; i < 4; ++i)
            af[i] = *(const short8*)&sA[(wm + i * 16 + col) * 32 + quad * 8];
        #pragma unroll
        for (int j = 0; j < 4; ++j)
            bf[j] = *(const short8*)&sB[(wn + j * 16 + col) * 32 + quad * 8];
        #pragma unroll
        for (int i = 0; i < 4; ++i)
            #pragma unroll
            for (int j = 0; j < 4; ++j)
                acc[i][j] = __builtin_amdgcn_mfma_f32_16x16x32_bf16(
                    af[i], bf[j], acc[i][j], 0, 0, 0);
        __syncthreads();
    }
}

// ---- prep: z<4 -> transpose x[b][c][n]->xT[b][n][c] bf16 ; z==4 -> W conv ----
__global__ __launch_bounds__(256)
void prep(const float* __restrict__ x,
          const float* __restrict__ Wq, const float* __restrict__ Wk,
          const float* __restrict__ Wv, const float* __restrict__ Wp,
          unsigned short* __restrict__ xT, unsigned short* __restrict__ Wb)
{
    if (blockIdx.z == 4) {
        const int idx = (blockIdx.y * 64 + blockIdx.x) * 256 + threadIdx.x; // 262144
        const int mat = idx >> 16;
        const int off = (idx & 65535) << 2;
        const float* src = (mat == 0 ? Wq : mat == 1 ? Wk : mat == 2 ? Wv : Wp) + off;
        const float4 f = *(const float4*)src;
        uint2 o;
        o.x = f2bf(f.x) | ((unsigned)f2bf(f.y) << 16);
        o.y = f2bf(f.z) | ((unsigned)f2bf(f.w) << 16);
        *(uint2*)&Wb[mat * 262144 + off] = o;
        return;
    }
    const int b = blockIdx.z;
    const int l = threadIdx.x & 63, w = threadIdx.x >> 6;
    const int n  = blockIdx.x * 64 + l;
    const int c0 = blockIdx.y * 32 + w * 8;
    const float* xp = x + (size_t)b * 2097152 + (size_t)c0 * 4096 + n;
    unsigned int p[4];
    #pragma unroll
    for (int j = 0; j < 4; ++j) {
        const unsigned short a  = f2bf(xp[(2 * j)     * 4096]);
        const unsigned short bb = f2bf(xp[(2 * j + 1) * 4096]);
        p[j] = a | ((unsigned)bb << 16);
    }
    uint4 v; v.x = p[0]; v.y = p[1]; v.z = p[2]; v.w = p[3];
    *(uint4*)&xT[(size_t)b * 2097152 + (size_t)n * 512 + c0] = v;
}

// ---- K1: q/k = W @ x natural [o][n]; V direct-stored as vT'[slab][e][kk'] ----
__global__ __launch_bounds__(256)
void gemm_qkv(const unsigned short* __restrict__ Wb,
              const unsigned short* __restrict__ xT,
              unsigned short* __restrict__ qb, unsigned short* __restrict__ kb,
              unsigned short* __restrict__ vT)
{
    __shared__ unsigned short sA[128 * 32], sB[128 * 32];

    const int z = blockIdx.z, wsel = z >> 2, b = z & 3;
    const unsigned short* A = Wb + wsel * 262144;
    const unsigned short* B = xT + (size_t)b * 2097152;
    const int m0 = blockIdx.y * 128, n0 = blockIdx.x * 128;

    f32x4 z4 = {0.f, 0.f, 0.f, 0.f};
    f32x4 acc[4][4];
    #pragma unroll
    for (int i = 0; i < 4; ++i)
        #pragma unroll
        for (int j = 0; j < 4; ++j) acc[i][j] = z4;

    mfma_core<512, 512, 512>(A, B, m0, n0, sA, sB, acc);

    const int lane = threadIdx.x & 63, wave = threadIdx.x >> 6;
    const int wm = (wave & 1) * 64, wn = (wave >> 1) * 64;
    const int col = lane & 15, quad = lane >> 4;

    if (wsel < 2) {
        unsigned short* C = (wsel == 0 ? qb : kb) + (size_t)b * 2097152;
        #pragma unroll
        for (int i = 0; i < 4; ++i)
            #pragma unroll
            for (int r = 0; r < 4; ++r) {
                const int row = m0 + wm + i * 16 + quad * 4 + r;
                #pragma unroll
                for (int j = 0; j < 4; ++j)
                    C[(size_t)row * 4096 + n0 + wn + j * 16 + col] = f2bf(acc[i][j][r]);
            }
    } else {
        // V tile: m = channel c -> head h = m0>>7; n -> s = n0>>10, e local.
        // Lane tile (i,j): 4 acc rows = 4 consecutive kk'. Direct uint2 store.
        const int h = m0 >> 7, s = n0 >> 10, e0 = n0 & 1023;
        unsigned short* dst = vT + (size_t)(b * 4 + h) * 524288 + s * 128;
        #pragma unroll
        for (int i = 0; i < 4; ++i) {
            const int kb2 = wm + i * 16 + quad * 4;
            #pragma unroll
            for (int j = 0; j < 4; ++j) {
                const int e = e0 + wn + j * 16 + col;
                uint2 o;
                o.x = f2bf(acc[i][j][0]) | ((unsigned)f2bf(acc[i][j][1]) << 16);
                o.y = f2bf(acc[i][j][2]) | ((unsigned)f2bf(acc[i][j][3]) << 16);
                *(uint2*)&dst[(size_t)e * 512 + kb2] = o;
            }
        }
    }
}

// ---- K2+K3 FUSED: P[qq][kk'] = softmax_row(scale * Q K^T) ----
// Block: 32 q-rows (m0), ALL 512 kk'. 8 waves; wave w owns kk' cols
// [w*64, w*64+64): acc[2][4] (i over 2x16 rows, j over 4x16 cols).
// K-loop over e=1024: sQ[32][32], sK[512][32] staged via global_load_lds
// (K rows fetched through the kk'->phys permutation).
__global__ __launch_bounds__(512)
void qk_softmax(const unsigned short* __restrict__ qb,
                const unsigned short* __restrict__ kb,
                unsigned short* __restrict__ Pb)
{
    __shared__ unsigned short sQ[32 * 32];     // 2 KB   [qrow][k]
    __shared__ unsigned short sK[512 * 32];    // 32 KB  [kk'][k]; reused as sP[32][512]
    __shared__ float sStat[8][32];

    const int tid = threadIdx.x;
    const int lane = tid & 63, wave = tid >> 6;   // 8 waves
    const int col = lane & 15, quad = lane >> 4;
    const int lr = lane >> 2, lc = lane & 3;      // staging: 16 rows x 4 chunks
    const int slab = blockIdx.y;
    const int m0 = blockIdx.x * 32;
    const int cbase = wave * 64;                  // this wave's kk' col offset

    const unsigned short* Q = qb + (size_t)slab * 524288;   // [512][1024]
    const unsigned short* K = kb + (size_t)slab * 524288;

    // Precompute per-lane global row addresses (k0-invariant parts)
    const unsigned short* gq = (wave < 2)
        ? Q + (size_t)(m0 + wave * 16 + lr) * 1024 + lc * 8 : nullptr;
    const unsigned short* gk[4];
    #pragma unroll
    for (int t = 0; t < 4; ++t) {
        const int kkp = (wave * 4 + t) * 16 + lr;
        const int phys = 4 * (kkp & 127) + (kkp >> 7);
        gk[t] = K + (size_t)phys * 1024 + lc * 8;
    }

    f32x4 z4 = {0.f, 0.f, 0.f, 0.f};
    f32x4 acc[2][4];
    #pragma unroll
    for (int i = 0; i < 2; ++i)
        #pragma unroll
        for (int j = 0; j < 4; ++j) acc[i][j] = z4;

    for (int k0 = 0; k0 < 1024; k0 += 32) {
        #pragma unroll
        for (int t = 0; t < 4; ++t)
            gl_lds16(gk[t] + k0, sK + (wave * 4 + t) * 512);   // 16 rows * 32 elems
        if (wave < 2)
            gl_lds16(gq + k0, sQ + wave * 512);
        __syncthreads();
        short8 af[2], bf[4];
        #pragma unroll
        for (int i = 0; i < 2; ++i)
            af[i] = *(const short8*)&sQ[(i * 16 + col) * 32 + quad * 8];
        #pragma unroll
        for (int j = 0; j < 4; ++j)
            bf[j] = *(const short8*)&sK[(cbase + j * 16 + col) * 32 + quad * 8];
        #pragma unroll
        for (int i = 0; i < 2; ++i)
            #pragma unroll
            for (int j = 0; j < 4; ++j)
                acc[i][j] = __builtin_amdgcn_mfma_f32_16x16x32_bf16(
                    af[i], bf[j], acc[i][j], 0, 0, 0);
        __syncthreads();
    }

    // ---- softmax over full rows (raw accs; scale applied inside exp) ----
    // lane holds rows i*16 + quad*4 + r, cols cbase + j*16 + col.
    float mx[2][4];
    #pragma unroll
    for (int i = 0; i < 2; ++i)
        #pragma unroll
        for (int r = 0; r < 4; ++r) {
            float m = acc[i][0][r];
            #pragma unroll
            for (int j = 1; j < 4; ++j) m = fmaxf(m, acc[i][j][r]);
            mx[i][r] = m;
        }
    #pragma unroll
    for (int s = 1; s < 16; s <<= 1)
        #pragma unroll
        for (int i = 0; i < 2; ++i)
            #pragma unroll
            for (int r = 0; r < 4; ++r)
                mx[i][r] = fmaxf(mx[i][r], __shfl_xor(mx[i][r], s));
    if (col == 0)
        #pragma unroll
        for (int i = 0; i < 2; ++i)
            #pragma unroll
            for (int r = 0; r < 4; ++r)
                sStat[wave][i * 16 + quad * 4 + r] = mx[i][r];
    __syncthreads();
    float M[2][4];
    #pragma unroll
    for (int i = 0; i < 2; ++i)
        #pragma unroll
        for (int r = 0; r < 4; ++r) {
            const int row = i * 16 + quad * 4 + r;
            float m = sStat[0][row];
            #pragma unroll
            for (int w = 1; w < 8; ++w) m = fmaxf(m, sStat[w][row]);
            M[i][r] = m;
        }
    __syncthreads();   // stats buffer about to be overwritten with sums

    float sm[2][4] = {};
    #pragma unroll
    for (int i = 0; i < 2; ++i)
        #pragma unroll
        for (int r = 0; r < 4; ++r) {
            #pragma unroll
            for (int j = 0; j < 4; ++j) {
                const float e = __expf((acc[i][j][r] - M[i][r]) * ATTN_SCALE);
                acc[i][j][r] = e;
                sm[i][r] += e;
            }
        }
    #pragma unroll
    for (int s = 1; s < 16; s <<= 1)
        #pragma unroll
        for (int i = 0; i < 2; ++i)
            #pragma unroll
            for (int r = 0; r < 4; ++r)
                sm[i][r] += __shfl_xor(sm[i][r], s);
    if (col == 0)
        #pragma unroll
        for (int i = 0; i < 2; ++i)
            #pragma unroll
            for (int r = 0; r < 4; ++r)
                sStat[wave][i * 16 + quad * 4 + r] = sm[i][r];
    __syncthreads();
    float inv[2][4];
    #pragma unroll
    for (int i = 0; i < 2; ++i)
        #pragma unroll
        for (int r = 0; r < 4; ++r) {
            const int row = i * 16 + quad * 4 + r;
            float s = sStat[0][row];
            #pragma unroll
            for (int w = 1; w < 8; ++w) s += sStat[w][row];
            inv[i][r] = 1.f / s;
        }

    // ---- write P bf16 into sP (=sK; safe: last sK read was before barrier) ----
    unsigned short* sP = sK;   // [32][512]
    #pragma unroll
    for (int i = 0; i < 2; ++i)
        #pragma unroll
        for (int r = 0; r < 4; ++r) {
            const int row = i * 16 + quad * 4 + r;
            #pragma unroll
            for (int j = 0; j < 4; ++j)
                sP[row * 512 + cbase + j * 16 + col] = f2bf(acc[i][j][r] * inv[i][r]);
        }
    __syncthreads();

    // ---- pack: coalesced uint4 stores of P rows ----
    unsigned short* dst = Pb + (size_t)slab * 262144 + (size_t)m0 * 512;
    #pragma unroll
    for (int u = 0; u < 4; ++u) {
        const int c = u * 512 + tid;          // 0..2047 chunks of 8 elems
        const int row = c >> 6, ch = c & 63;
        *(uint4*)&dst[(size_t)row * 512 + ch * 8] = *(const uint4*)&sP[row * 512 + ch * 8];
    }
}

// ---- K4: O = P V' per slab; scatter into yT[n][c] via LDS tile ----
__global__ __launch_bounds__(256)
void gemm_pv(const unsigned short* __restrict__ Pb,
             const unsigned short* __restrict__ vT,
             unsigned short* __restrict__ yT)
{
    __shared__ unsigned short sT[128 * 136];          // 34816 B; aliases staging
    unsigned short* sA = sT;
    unsigned short* sB = sT + 4096;
    const int z = blockIdx.z, b = z >> 2, hh = z & 3;
    const unsigned short* A = Pb + (size_t)z * 262144;   // [512][512] kk'-cols
    const unsigned short* B = vT + (size_t)z * 524288;   // [1024][512] kk'-rows
    unsigned short* yTb = yT + (size_t)b * 2097152;
    const int m0 = blockIdx.y * 128;   // qq
    const int n0 = blockIdx.x * 128;   // e

    f32x4 z4 = {0.f, 0.f, 0.f, 0.f};
    f32x4 acc[4][4];
    #pragma unroll
    for (int i = 0; i < 4; ++i)
        #pragma unroll
        for (int j = 0; j < 4; ++j) acc[i][j] = z4;

    mfma_core<512, 512, 512>(A, B, m0, n0, sA, sB, acc);

    const int tid = threadIdx.x;
    const int lane = tid & 63, wave = tid >> 6;
    const int wm = (wave & 1) * 64, wn = (wave >> 1) * 64;
    const int col = lane & 15, quad = lane >> 4;

    // D tile -> LDS [qq_local][e_local], pad 136
    #pragma unroll
    for (int i = 0; i < 4; ++i)
        #pragma unroll
        for (int r = 0; r < 4; ++r) {
            const int rr = wm + i * 16 + quad * 4 + r;
            #pragma unroll
            for (int j = 0; j < 4; ++j)
                sT[rr * 136 + wn + j * 16 + col] = f2bf(acc[i][j][r]);
        }
    __syncthreads();

    // pack 16-elem c-runs: yT[(s<<9)+qq][hh*128 + (n0>>3) + tt], tt=0..15
    #pragma unroll
    for (int k = 0; k < 4; ++k) {
        const int rid = k * 256 + tid;       // 0..1023
        const int qq_l = rid >> 3, s = rid & 7;
        const unsigned short* Trow = sT + qq_l * 136;
        unsigned int p[8];
        #pragma unroll
        for (int t = 0; t < 8; ++t) {
            const unsigned int a  = Trow[s + 8 * (2 * t)];
            const unsigned int bb = Trow[s + 8 * (2 * t + 1)];
            p[t] = a | (bb << 16);
        }
        const size_t base = (size_t)((s << 9) + m0 + qq_l) * 512 + hh * 128 + (n0 >> 3);
        uint4 lo; lo.x = p[0]; lo.y = p[1]; lo.z = p[2]; lo.w = p[3];
        uint4 hi; hi.x = p[4]; hi.y = p[5]; hi.z = p[6]; hi.w = p[7];
        *(uint4*)&yTb[base]     = lo;
        *(uint4*)&yTb[base + 8] = hi;
    }
}

// ---- K5: out = Wproj @ y + bias + x (NT vs yT), fp32 out ----
__global__ __launch_bounds__(256)
void gemm_proj(const unsigned short* __restrict__ Wpb,
               const unsigned short* __restrict__ yT,
               const float* __restrict__ bias, const float* __restrict__ x,
               float* __restrict__ out)
{
    __shared__ unsigned short sA[128 * 32], sB[128 * 32];
    const int b = blockIdx.z;
    const unsigned short* B = yT + (size_t)b * 2097152;  // [4096][512]
    const int m0 = blockIdx.y * 128, n0 = blockIdx.x * 128;

    f32x4 z4 = {0.f, 0.f, 0.f, 0.f};
    f32x4 acc[4][4];
    #pragma unroll
    for (int i = 0; i < 4; ++i)
        #pragma unroll
        for (int j = 0; j < 4; ++j) acc[i][j] = z4;

    mfma_core<512, 512, 512>(Wpb, B, m0, n0, sA, sB, acc);

    const int lane = threadIdx.x & 63, wave = threadIdx.x >> 6;
    const int wm = (wave & 1) * 64, wn = (wave >> 1) * 64;
    const int col = lane & 15, quad = lane >> 4;
    const size_t boff = (size_t)b * 2097152;
    #pragma unroll
    for (int i = 0; i < 4; ++i)
        #pragma unroll
        for (int r = 0; r < 4; ++r) {
            const int row = m0 + wm + i * 16 + quad * 4 + r;
            const float bi = bias[row];
            #pragma unroll
            for (int j = 0; j < 4; ++j) {
                const size_t idx = boff + (size_t)row * 4096 + n0 + wn + j * 16 + col;
                out[idx] = acc[i][j][r] + bi + x[idx];
            }
        }
}

extern "C" void kernel_launch(void* const* d_in, const int* in_sizes, int n_in,
                              void* d_out, int out_size, void* d_ws, size_t ws_size,
                              hipStream_t stream) {
    const float* x     = (const float*)d_in[0];
    const float* Wq    = (const float*)d_in[1];
    const float* Wk    = (const float*)d_in[2];
    const float* Wv    = (const float*)d_in[3];
    const float* Wproj = (const float*)d_in[4];
    const float* bproj = (const float*)d_in[5];
    float* out = (float*)d_out;

    char* w = (char*)d_ws;
    unsigned short* xT = (unsigned short*)(w + 0);          // 16 MB [b][n][c]
    unsigned short* qb = (unsigned short*)(w + 16777216);   // 16 MB [b][o][n]
    unsigned short* kb = (unsigned short*)(w + 33554432);   // 16 MB
    unsigned short* vT = (unsigned short*)(w + 50331648);   // 16 MB [slab][e][kk']
    unsigned short* Pb = (unsigned short*)(w + 67108864);   //  8 MB [slab][qq][kk']
    unsigned short* Wb = (unsigned short*)(w + 75497472);   //  2 MB
    unsigned short* yT = xT;   // xT dead after gemm_qkv

    prep       <<<dim3(64, 16, 5),  256, 0, stream>>>(x, Wq, Wk, Wv, Wproj, xT, Wb);
    gemm_qkv   <<<dim3(32, 4, 12),  256, 0, stream>>>(Wb, xT, qb, kb, vT);
    qk_softmax <<<dim3(16, 16),     512, 0, stream>>>(qb, kb, Pb);
    gemm_pv    <<<dim3(8, 4, 16),   256, 0, stream>>>(Pb, vT, yT);
    gemm_proj  <<<dim3(32, 4, 4),   256, 0, stream>>>(Wb + 3 * 262144, yT, bproj, x, out);
}

// Round 7
// 206.862 us; speedup vs baseline: 1.0216x; 1.0216x over previous
//
#include <hip/hip_runtime.h>
#include <stdint.h>

// SelfCrossAttn bf16-MFMA pipeline v7. b=4, c=512, N=4096, HEADS=4.
// All GEMMs NT: C[m][n] = sum_k A[m][k]*B[n][k], operands k-contiguous.
// kk' = s*128+t permutation (s=n>>10, t=c&127) applied uniformly to P cols
// and vT' rows; sum over kk is order-agnostic.
//  prep    : W* fp32->bf16 (Wb) ; x[b][c][n] -> xT[b][n][c] bf16
//  gemm_qkv: z<4: FUSED q+k (shared xT B-tile staged once, 2 acc sets);
//            z>=4: V direct-stored as vT'[slab][e][kk'] (uint2 stores)
//  gemm_qk : split-K x2: S_half[qq][kk'] partials (fp32), K staged via perm
//  softmax : rows of S0+S1 -> P bf16
//  gemm_pv : O = P.V' (A=P[qq][kk'], B=vT'[e][kk']); scatters into yT[n][c]
//  gemm_proj: out = Wproj @ y + bias + x (NT vs yT), fp32

typedef __attribute__((ext_vector_type(8))) short short8;
typedef __attribute__((ext_vector_type(4))) float f32x4;

typedef const __attribute__((address_space(1))) unsigned int* gas_ptr;
typedef __attribute__((address_space(3))) unsigned int* las_ptr;

#define ATTN_SCALE 0.08838834764831845f   // 128^-0.5

__device__ __forceinline__ unsigned short f2bf(float f) {
    union { float f; unsigned int u; } c; c.f = f;
    unsigned int u = c.u;
    u += 0x7fffu + ((u >> 16) & 1u);      // RNE
    return (unsigned short)(u >> 16);
}

__device__ __forceinline__ void gl_lds16(const void* g, void* l) {
    __builtin_amdgcn_global_load_lds((gas_ptr)(uintptr_t)g, (las_ptr)(uintptr_t)l,
                                     16, 0, 0);
}

// ---- shared MFMA core: 128x128 C-tile, 4 waves, BK=32, 16x16x32 bf16 ----
// PERMB: B rows are logical kk' -> physical slab row 4*(kk'&127) + (kk'>>7).
template<int LDA, int LDB, int KDIM, bool PERMB = false>
__device__ __forceinline__ void mfma_core(
    const unsigned short* __restrict__ A,
    const unsigned short* __restrict__ B,
    int m0, int n0,
    unsigned short* __restrict__ sA, unsigned short* __restrict__ sB,
    f32x4 acc[4][4])
{
    const int tid  = threadIdx.x;
    const int lane = tid & 63, wave = tid >> 6;
    const int lr = lane >> 2, lc = lane & 3;       // staging: 16 rows x 4 chunks
    const int wm = (wave & 1) * 64, wn = (wave >> 1) * 64;
    const int col = lane & 15, quad = lane >> 4;

    const unsigned short* ga = A + (size_t)(m0 + 32 * wave + lr) * LDA + lc * 8;
    int rb0 = n0 + 32 * wave + lr;
    int rb1 = rb0 + 16;
    if (PERMB) {
        rb0 = 4 * (rb0 & 127) + (rb0 >> 7);
        rb1 = 4 * (rb1 & 127) + (rb1 >> 7);
    }
    const unsigned short* gb0 = B + (size_t)rb0 * LDB + lc * 8;
    const unsigned short* gb1 = B + (size_t)rb1 * LDB + lc * 8;

    unsigned short* la0 = sA + (32 * wave) * 32;
    unsigned short* la1 = sA + (32 * wave + 16) * 32;
    unsigned short* lb0 = sB + (32 * wave) * 32;
    unsigned short* lb1 = sB + (32 * wave + 16) * 32;

    for (int k0 = 0; k0 < KDIM; k0 += 32) {
        gl_lds16(ga + k0,            la0);
        gl_lds16(ga + k0 + 16 * LDA, la1);
        gl_lds16(gb0 + k0,           lb0);
        gl_lds16(gb1 + k0,           lb1);
        __syncthreads();
        short8 af[4], bf[4];
        #pragma unroll
        for (int i = 0; i < 4; ++i)
            af[i] = *(const short8*)&sA[(wm + i * 16 + col) * 32 + quad * 8];
        #pragma unroll
        for (int j = 0; j < 4; ++j)
            bf[j] = *(const short8*)&sB[(wn + j * 16 + col) * 32 + quad * 8];
        #pragma unroll
        for (int i = 0; i < 4; ++i)
            #pragma unroll
            for (int j = 0; j < 4; ++j)
                acc[i][j] = __builtin_amdgcn_mfma_f32_16x16x32_bf16(
                    af[i], bf[j], acc[i][j], 0, 0, 0);
        __syncthreads();
    }
}

// ---- prep: z<4 -> transpose x[b][c][n]->xT[b][n][c] bf16 ; z==4 -> W conv ----
__global__ __launch_bounds__(256)
void prep(const float* __restrict__ x,
          const float* __restrict__ Wq, const float* __restrict__ Wk,
          const float* __restrict__ Wv, const float* __restrict__ Wp,
          unsigned short* __restrict__ xT, unsigned short* __restrict__ Wb)
{
    if (blockIdx.z == 4) {
        const int idx = (blockIdx.y * 64 + blockIdx.x) * 256 + threadIdx.x; // 262144
        const int mat = idx >> 16;
        const int off = (idx & 65535) << 2;
        const float* src = (mat == 0 ? Wq : mat == 1 ? Wk : mat == 2 ? Wv : Wp) + off;
        const float4 f = *(const float4*)src;
        uint2 o;
        o.x = f2bf(f.x) | ((unsigned)f2bf(f.y) << 16);
        o.y = f2bf(f.z) | ((unsigned)f2bf(f.w) << 16);
        *(uint2*)&Wb[mat * 262144 + off] = o;
        return;
    }
    const int b = blockIdx.z;
    const int l = threadIdx.x & 63, w = threadIdx.x >> 6;
    const int n  = blockIdx.x * 64 + l;
    const int c0 = blockIdx.y * 32 + w * 8;
    const float* xp = x + (size_t)b * 2097152 + (size_t)c0 * 4096 + n;
    unsigned int p[4];
    #pragma unroll
    for (int j = 0; j < 4; ++j) {
        const unsigned short a  = f2bf(xp[(2 * j)     * 4096]);
        const unsigned short bb = f2bf(xp[(2 * j + 1) * 4096]);
        p[j] = a | ((unsigned)bb << 16);
    }
    uint4 v; v.x = p[0]; v.y = p[1]; v.z = p[2]; v.w = p[3];
    *(uint4*)&xT[(size_t)b * 2097152 + (size_t)n * 512 + c0] = v;
}

// ---- K1: z<4 fused q+k (shared B staging); z>=4 V -> vT'[slab][e][kk'] ----
__global__ __launch_bounds__(256, 2)
void gemm_qkv(const unsigned short* __restrict__ Wb,
              const unsigned short* __restrict__ xT,
              unsigned short* __restrict__ qb, unsigned short* __restrict__ kb,
              unsigned short* __restrict__ vT)
{
    __shared__ unsigned short smem[3 * 4096];   // 24 KB

    const int z = blockIdx.z, b = z & 3;
    const unsigned short* B = xT + (size_t)b * 2097152;
    const int m0 = blockIdx.y * 128, n0 = blockIdx.x * 128;

    const int tid = threadIdx.x;
    const int lane = tid & 63, wave = tid >> 6;
    const int lr = lane >> 2, lc = lane & 3;
    const int wm = (wave & 1) * 64, wn = (wave >> 1) * 64;
    const int col = lane & 15, quad = lane >> 4;

    f32x4 z4 = {0.f, 0.f, 0.f, 0.f};

    if (z < 4) {
        // -------- fused Q+K: one B staging, two A streams, two acc sets ----
        unsigned short* sQ = smem;              // A_q tile [128][32]
        unsigned short* sK = smem + 4096;       // A_k tile
        unsigned short* sB = smem + 8192;       // B tile

        const unsigned short* gaq = Wb           + (size_t)(m0 + 32 * wave + lr) * 512 + lc * 8;
        const unsigned short* gak = (Wb + 262144) + (size_t)(m0 + 32 * wave + lr) * 512 + lc * 8;
        const unsigned short* gb  = B + (size_t)(n0 + 32 * wave + lr) * 512 + lc * 8;
        unsigned short* lq0 = sQ + (32 * wave) * 32;
        unsigned short* lq1 = sQ + (32 * wave + 16) * 32;
        unsigned short* lk0 = sK + (32 * wave) * 32;
        unsigned short* lk1 = sK + (32 * wave + 16) * 32;
        unsigned short* lb0 = sB + (32 * wave) * 32;
        unsigned short* lb1 = sB + (32 * wave + 16) * 32;

        f32x4 accq[4][4], acck[4][4];
        #pragma unroll
        for (int i = 0; i < 4; ++i)
            #pragma unroll
            for (int j = 0; j < 4; ++j) { accq[i][j] = z4; acck[i][j] = z4; }

        for (int k0 = 0; k0 < 512; k0 += 32) {
            gl_lds16(gaq + k0,            lq0);
            gl_lds16(gaq + k0 + 16 * 512, lq1);
            gl_lds16(gak + k0,            lk0);
            gl_lds16(gak + k0 + 16 * 512, lk1);
            gl_lds16(gb + k0,             lb0);
            gl_lds16(gb + k0 + 16 * 512,  lb1);
            __syncthreads();
            short8 afq[4], afk[4], bf[4];
            #pragma unroll
            for (int j = 0; j < 4; ++j)
                bf[j] = *(const short8*)&sB[(wn + j * 16 + col) * 32 + quad * 8];
            #pragma unroll
            for (int i = 0; i < 4; ++i) {
                afq[i] = *(const short8*)&sQ[(wm + i * 16 + col) * 32 + quad * 8];
                afk[i] = *(const short8*)&sK[(wm + i * 16 + col) * 32 + quad * 8];
            }
            #pragma unroll
            for (int i = 0; i < 4; ++i)
                #pragma unroll
                for (int j = 0; j < 4; ++j) {
                    accq[i][j] = __builtin_amdgcn_mfma_f32_16x16x32_bf16(
                        afq[i], bf[j], accq[i][j], 0, 0, 0);
                    acck[i][j] = __builtin_amdgcn_mfma_f32_16x16x32_bf16(
                        afk[i], bf[j], acck[i][j], 0, 0, 0);
                }
            __syncthreads();
        }

        unsigned short* Cq = qb + (size_t)b * 2097152;
        unsigned short* Ck = kb + (size_t)b * 2097152;
        #pragma unroll
        for (int i = 0; i < 4; ++i)
            #pragma unroll
            for (int r = 0; r < 4; ++r) {
                const int row = m0 + wm + i * 16 + quad * 4 + r;
                #pragma unroll
                for (int j = 0; j < 4; ++j) {
                    const size_t idx = (size_t)row * 4096 + n0 + wn + j * 16 + col;
                    Cq[idx] = f2bf(accq[i][j][r]);
                    Ck[idx] = f2bf(acck[i][j][r]);
                }
            }
    } else {
        // -------- V: direct-store vT'[b*4+h][e][kk'] ----
        unsigned short* sA = smem;
        unsigned short* sB = smem + 4096;
        const unsigned short* A = Wb + 2 * 262144;

        f32x4 acc[4][4];
        #pragma unroll
        for (int i = 0; i < 4; ++i)
            #pragma unroll
            for (int j = 0; j < 4; ++j) acc[i][j] = z4;

        mfma_core<512, 512, 512>(A, B, m0, n0, sA, sB, acc);

        const int h = m0 >> 7, s = n0 >> 10, e0 = n0 & 1023;
        unsigned short* dst = vT + (size_t)(b * 4 + h) * 524288 + s * 128;
        #pragma unroll
        for (int i = 0; i < 4; ++i) {
            const int kb2 = wm + i * 16 + quad * 4;
            #pragma unroll
            for (int j = 0; j < 4; ++j) {
                const int e = e0 + wn + j * 16 + col;
                uint2 o;
                o.x = f2bf(acc[i][j][0]) | ((unsigned)f2bf(acc[i][j][1]) << 16);
                o.y = f2bf(acc[i][j][2]) | ((unsigned)f2bf(acc[i][j][3]) << 16);
                *(uint2*)&dst[(size_t)e * 512 + kb2] = o;
            }
        }
    }
}

// ---- K2: split-K x2: S_half[qq][kk'] = scale * Q K^T partial ----
__global__ __launch_bounds__(256)
void gemm_qk(const unsigned short* __restrict__ qb,
             const unsigned short* __restrict__ kb,
             float* __restrict__ S)
{
    __shared__ unsigned short sA[128 * 32], sB[128 * 32];
    const int z = blockIdx.z;                 // slab*2 + half
    const int slab = z >> 1, half = z & 1;
    const unsigned short* A = qb + (size_t)slab * 524288 + half * 512;
    const unsigned short* B = kb + (size_t)slab * 524288 + half * 512;
    float* Sp = S + (size_t)half * 4194304 + (size_t)slab * 262144;
    const int m0 = blockIdx.y * 128, n0 = blockIdx.x * 128;

    f32x4 z4 = {0.f, 0.f, 0.f, 0.f};
    f32x4 acc[4][4];
    #pragma unroll
    for (int i = 0; i < 4; ++i)
        #pragma unroll
        for (int j = 0; j < 4; ++j) acc[i][j] = z4;

    mfma_core<1024, 1024, 512, true>(A, B, m0, n0, sA, sB, acc);

    const int lane = threadIdx.x & 63, wave = threadIdx.x >> 6;
    const int wm = (wave & 1) * 64, wn = (wave >> 1) * 64;
    const int col = lane & 15, quad = lane >> 4;
    #pragma unroll
    for (int i = 0; i < 4; ++i)
        #pragma unroll
        for (int r = 0; r < 4; ++r) {
            const int row = m0 + wm + i * 16 + quad * 4 + r;
            #pragma unroll
            for (int j = 0; j < 4; ++j)
                Sp[(size_t)row * 512 + n0 + wn + j * 16 + col] =
                    acc[i][j][r] * ATTN_SCALE;
        }
}

// ---- K3: row softmax of (S0+S1) -> P (bf16), one wave per 512-row ----
__global__ __launch_bounds__(256)
void softmax_rows(const float* __restrict__ S, unsigned short* __restrict__ P)
{
    const int wave = threadIdx.x >> 6, lane = threadIdx.x & 63;
    const int row  = blockIdx.x * 4 + wave;          // 8192 rows
    const float* p0 = S + (size_t)row * 512;
    const float* p1 = p0 + 4194304;
    unsigned short* o = P + (size_t)row * 512;

    float vals[8];
    float m = -1e30f;
    #pragma unroll
    for (int t = 0; t < 8; ++t) {
        vals[t] = p0[lane + t * 64] + p1[lane + t * 64];
        m = fmaxf(m, vals[t]);
    }
    #pragma unroll
    for (int s = 32; s > 0; s >>= 1) m = fmaxf(m, __shfl_xor(m, s));
    float sum = 0.f;
    #pragma unroll
    for (int t = 0; t < 8; ++t) { vals[t] = __expf(vals[t] - m); sum += vals[t]; }
    #pragma unroll
    for (int s = 32; s > 0; s >>= 1) sum += __shfl_xor(sum, s);
    const float inv = 1.f / sum;
    #pragma unroll
    for (int t = 0; t < 8; ++t) o[lane + t * 64] = f2bf(vals[t] * inv);
}

// ---- K4: O = P V' per slab; scatter into yT[n][c] via LDS tile ----
__global__ __launch_bounds__(256)
void gemm_pv(const unsigned short* __restrict__ Pb,
             const unsigned short* __restrict__ vT,
             unsigned short* __restrict__ yT)
{
    __shared__ unsigned short sT[128 * 136];          // 34816 B; aliases staging
    unsigned short* sA = sT;
    unsigned short* sB = sT + 4096;
    const int z = blockIdx.z, b = z >> 2, hh = z & 3;
    const unsigned short* A = Pb + (size_t)z * 262144;   // [512][512] kk'-cols
    const unsigned short* B = vT + (size_t)z * 524288;   // [1024][512] kk'-rows
    unsigned short* yTb = yT + (size_t)b * 2097152;
    const int m0 = blockIdx.y * 128;   // qq
    const int n0 = blockIdx.x * 128;   // e

    f32x4 z4 = {0.f, 0.f, 0.f, 0.f};
    f32x4 acc[4][4];
    #pragma unroll
    for (int i = 0; i < 4; ++i)
        #pragma unroll
        for (int j = 0; j < 4; ++j) acc[i][j] = z4;

    mfma_core<512, 512, 512>(A, B, m0, n0, sA, sB, acc);

    const int tid = threadIdx.x;
    const int lane = tid & 63, wave = tid >> 6;
    const int wm = (wave & 1) * 64, wn = (wave >> 1) * 64;
    const int col = lane & 15, quad = lane >> 4;

    // D tile -> LDS [qq_local][e_local], pad 136
    #pragma unroll
    for (int i = 0; i < 4; ++i)
        #pragma unroll
        for (int r = 0; r < 4; ++r) {
            const int rr = wm + i * 16 + quad * 4 + r;
            #pragma unroll
            for (int j = 0; j < 4; ++j)
                sT[rr * 136 + wn + j * 16 + col] = f2bf(acc[i][j][r]);
        }
    __syncthreads();

    // pack 16-elem c-runs: yT[(s<<9)+qq][hh*128 + (n0>>3) + tt], tt=0..15
    #pragma unroll
    for (int k = 0; k < 4; ++k) {
        const int rid = k * 256 + tid;       // 0..1023
        const int qq_l = rid >> 3, s = rid & 7;
        const unsigned short* Trow = sT + qq_l * 136;
        unsigned int p[8];
        #pragma unroll
        for (int t = 0; t < 8; ++t) {
            const unsigned int a  = Trow[s + 8 * (2 * t)];
            const unsigned int bb = Trow[s + 8 * (2 * t + 1)];
            p[t] = a | (bb << 16);
        }
        const size_t base = (size_t)((s << 9) + m0 + qq_l) * 512 + hh * 128 + (n0 >> 3);
        uint4 lo; lo.x = p[0]; lo.y = p[1]; lo.z = p[2]; lo.w = p[3];
        uint4 hi; hi.x = p[4]; hi.y = p[5]; hi.z = p[6]; hi.w = p[7];
        *(uint4*)&yTb[base]     = lo;
        *(uint4*)&yTb[base + 8] = hi;
    }
}

// ---- K5: out = Wproj @ y + bias + x (NT vs yT), fp32 out ----
__global__ __launch_bounds__(256)
void gemm_proj(const unsigned short* __restrict__ Wpb,
               const unsigned short* __restrict__ yT,
               const float* __restrict__ bias, const float* __restrict__ x,
               float* __restrict__ out)
{
    __shared__ unsigned short sA[128 * 32], sB[128 * 32];
    const int b = blockIdx.z;
    const unsigned short* B = yT + (size_t)b * 2097152;  // [4096][512]
    const int m0 = blockIdx.y * 128, n0 = blockIdx.x * 128;

    f32x4 z4 = {0.f, 0.f, 0.f, 0.f};
    f32x4 acc[4][4];
    #pragma unroll
    for (int i = 0; i < 4; ++i)
        #pragma unroll
        for (int j = 0; j < 4; ++j) acc[i][j] = z4;

    mfma_core<512, 512, 512>(Wpb, B, m0, n0, sA, sB, acc);

    const int lane = threadIdx.x & 63, wave = threadIdx.x >> 6;
    const int wm = (wave & 1) * 64, wn = (wave >> 1) * 64;
    const int col = lane & 15, quad = lane >> 4;
    const size_t boff = (size_t)b * 2097152;
    #pragma unroll
    for (int i = 0; i < 4; ++i)
        #pragma unroll
        for (int r = 0; r < 4; ++r) {
            const int row = m0 + wm + i * 16 + quad * 4 + r;
            const float bi = bias[row];
            #pragma unroll
            for (int j = 0; j < 4; ++j) {
                const size_t idx = boff + (size_t)row * 4096 + n0 + wn + j * 16 + col;
                out[idx] = acc[i][j][r] + bi + x[idx];
            }
        }
}

extern "C" void kernel_launch(void* const* d_in, const int* in_sizes, int n_in,
                              void* d_out, int out_size, void* d_ws, size_t ws_size,
                              hipStream_t stream) {
    const float* x     = (const float*)d_in[0];
    const float* Wq    = (const float*)d_in[1];
    const float* Wk    = (const float*)d_in[2];
    const float* Wv    = (const float*)d_in[3];
    const float* Wproj = (const float*)d_in[4];
    const float* bproj = (const float*)d_in[5];
    float* out = (float*)d_out;

    char* w = (char*)d_ws;
    unsigned short* xT = (unsigned short*)(w + 0);          // 16 MB [b][n][c]
    unsigned short* qb = (unsigned short*)(w + 16777216);   // 16 MB [b][o][n]
    unsigned short* kb = (unsigned short*)(w + 33554432);   // 16 MB
    unsigned short* vT = (unsigned short*)(w + 50331648);   // 16 MB [slab][e][kk']
    float*          S  = (float*)        (w + 67108864);    // 32 MB fp32 (2 halves)
    unsigned short* Pb = (unsigned short*)(w + 100663296);  //  8 MB
    unsigned short* Wb = (unsigned short*)(w + 109051904);  //  2 MB
    unsigned short* yT = xT;   // xT dead after gemm_qkv

    prep        <<<dim3(64, 16, 5),  256, 0, stream>>>(x, Wq, Wk, Wv, Wproj, xT, Wb);
    gemm_qkv    <<<dim3(32, 4, 8),   256, 0, stream>>>(Wb, xT, qb, kb, vT);
    gemm_qk     <<<dim3(4, 4, 32),   256, 0, stream>>>(qb, kb, S);
    softmax_rows<<<dim3(2048),       256, 0, stream>>>(S, Pb);
    gemm_pv     <<<dim3(8, 4, 16),   256, 0, stream>>>(Pb, vT, yT);
    gemm_proj   <<<dim3(32, 4, 4),   256, 0, stream>>>(Wb + 3 * 262144, yT, bproj, x, out);
}